// Round 1
// baseline (533.403 us; speedup 1.0000x reference)
//
#include <hip/hip_runtime.h>
#include <hip/hip_bf16.h>

typedef __attribute__((ext_vector_type(8))) short bf16x8;
typedef __attribute__((ext_vector_type(4))) float f32x4;

#define B_ 4
#define N_ 16000
#define C_ 128
#define K_ 16
#define D_ 4
#define H_ 512
#define R_ (B_*N_)      // 64000 rows
#define TM 64           // rows per block tile
#define EPSV 1e-5f

__device__ __forceinline__ ushort f2bf(float f) {
    uint32_t b = __builtin_bit_cast(uint32_t, f);
    b += 0x7fffu + ((b >> 16) & 1u);   // RNE
    return (ushort)(b >> 16);
}
__device__ __forceinline__ float bf2f(ushort u) {
    return __builtin_bit_cast(float, (uint32_t)u << 16);
}
__device__ __forceinline__ float gelu_tanh(float v) {
    // jax.nn.gelu default (approximate=True)
    return 0.5f * v * (1.0f + tanhf(0.7978845608028654f * (v + 0.044715f * v * v * v)));
}

// ---------------- prep: transpose weights to Bt[n][k] bf16, fold BN ----------------
__global__ void prep_kernel(
    const float* __restrict__ mlp_W1, const float* __restrict__ mlp_b1,
    const float* __restrict__ mlp_W2, const float* __restrict__ mlp_g,
    const float* __restrict__ mlp_be, const float* __restrict__ mlp_m,
    const float* __restrict__ mlp_v,
    const float* __restrict__ vfr_W, const float* __restrict__ vfr_g,
    const float* __restrict__ vfr_be, const float* __restrict__ vfr_m,
    const float* __restrict__ vfr_v,
    const float* __restrict__ ffn_W1, const float* __restrict__ ffn_b1,
    const float* __restrict__ ffn_W2, const float* __restrict__ ffn_g,
    const float* __restrict__ ffn_be, const float* __restrict__ ffn_m,
    const float* __restrict__ ffn_v,
    ushort* __restrict__ w1t, ushort* __restrict__ w2t, ushort* __restrict__ wvt,
    float* __restrict__ b1a, float* __restrict__ fs, float* __restrict__ fb,
    float* __restrict__ vs, float* __restrict__ vb)
{
    int i = blockIdx.x * 256 + threadIdx.x;
    const int NW = 5 * H_ * C_;   // 327680
    if (i < NW) {                 // w1t[f][h][c] = W1_f[c][h]
        int f = i / (H_*C_), e = i % (H_*C_);
        int h = e / C_, c = e % C_;
        const float* src = (f == 0) ? mlp_W1 : ffn_W1 + (size_t)(f-1)*C_*H_;
        w1t[i] = f2bf(src[(size_t)c*H_ + h]);
        return;
    }
    i -= NW;
    if (i < NW) {                 // w2t[f][c][h] = W2_f[h][c]
        int f = i / (H_*C_), e = i % (H_*C_);
        int c = e / H_, h = e % H_;
        const float* src = (f == 0) ? mlp_W2 : ffn_W2 + (size_t)(f-1)*H_*C_;
        w2t[i] = f2bf(src[(size_t)h*C_ + c]);
        return;
    }
    i -= NW;
    if (i < D_*C_*C_) {           // wvt[d][cout][k] = W[d][k][cout]
        int d = i / (C_*C_), e = i % (C_*C_);
        int co = e / C_, k = e % C_;
        wvt[i] = f2bf(vfr_W[(size_t)d*C_*C_ + (size_t)k*C_ + co]);
        return;
    }
    i -= D_*C_*C_;
    if (i < 5*H_) {               // biases
        int f = i / H_, h = i % H_;
        b1a[i] = (f == 0) ? mlp_b1[h] : ffn_b1[(f-1)*H_ + h];
        return;
    }
    i -= 5*H_;
    if (i < 5*C_) {               // ffn BN: y*s + b
        int f = i / C_, c = i % C_;
        float g  = (f==0) ? mlp_g[c]  : ffn_g[(f-1)*C_ + c];
        float be = (f==0) ? mlp_be[c] : ffn_be[(f-1)*C_ + c];
        float m  = (f==0) ? mlp_m[c]  : ffn_m[(f-1)*C_ + c];
        float v  = (f==0) ? mlp_v[c]  : ffn_v[(f-1)*C_ + c];
        float s = g * rsqrtf(v + EPSV);
        fs[i] = s; fb[i] = be - m * s;
        return;
    }
    i -= 5*C_;
    if (i < D_*C_) {              // vfr BN
        float s = vfr_g[i] * rsqrtf(vfr_v[i] + EPSV);
        vs[i] = s; vb[i] = vfr_be[i] - vfr_m[i] * s;
    }
}

// ---------------- fused FFN: x_out = x_in + BN(gelu(x@W1+b1)@W2) ----------------
// 64-row tile per block, H chunked in 64-col slices; 4 waves, each owns a 16-row strip.
__global__ __launch_bounds__(256, 2) void ffn_kernel(
    const float* __restrict__ xin, float* __restrict__ xout,
    const ushort* __restrict__ W1t,   // [H][C] bf16 (Bt for GEMM1)
    const ushort* __restrict__ W2t,   // [C][H] bf16 (Bt for GEMM2)
    const float* __restrict__ b1,
    const float* __restrict__ bns, const float* __restrict__ bnb)
{
    __shared__ __attribute__((aligned(16))) char lds[16384 + 16384 + 16384 + 8192];
    char* Xs  = lds;           // [64][128 bf16], 256 B rows, swizzled
    char* W1s = lds + 16384;   // [64 h][128 c] bf16, 256 B rows
    char* W2s = lds + 32768;   // [128 c][64 h] bf16, 128 B rows
    char* Hs  = lds + 49152;   // [64 m][64 h] bf16, 128 B rows

    const int tid  = threadIdx.x;
    const int m0   = blockIdx.x * TM;
    const int wv   = tid >> 6;
    const int lane = tid & 63;
    const int lr   = lane & 15;
    const int lh   = lane >> 4;    // 0..3

    // stage X tile (fp32 -> bf16, swizzled)
    #pragma unroll
    for (int it = 0; it < 4; ++it) {
        int idx = it * 2048 + tid * 8;
        int r = idx >> 7, c = idx & 127;
        const float* gp = xin + (size_t)(m0 + r) * C_ + c;
        float4 v0 = *(const float4*)gp;
        float4 v1 = *(const float4*)(gp + 4);
        bf16x8 pk;
        pk[0]=(short)f2bf(v0.x); pk[1]=(short)f2bf(v0.y);
        pk[2]=(short)f2bf(v0.z); pk[3]=(short)f2bf(v0.w);
        pk[4]=(short)f2bf(v1.x); pk[5]=(short)f2bf(v1.y);
        pk[6]=(short)f2bf(v1.z); pk[7]=(short)f2bf(v1.w);
        *(bf16x8*)(Xs + r*256 + ((c*2) ^ ((r&7)<<4))) = pk;
    }

    f32x4 acc2[8];
    #pragma unroll
    for (int i = 0; i < 8; ++i) acc2[i] = (f32x4){0.f,0.f,0.f,0.f};

    for (int hc = 0; hc < 8; ++hc) {
        const int h0 = hc * 64;
        __syncthreads();   // protect W tiles from previous chunk's reads (and Xs on iter 0)
        #pragma unroll
        for (int it = 0; it < 4; ++it) {           // W1s: 64 rows x 256 B
            int e = it * 256 + tid;
            int r = e >> 4; int cb = (e & 15) << 4;
            uint4 w = *(const uint4*)((const char*)(W1t + (size_t)(h0 + r) * C_) + cb);
            *(uint4*)(W1s + r*256 + (cb ^ ((r&7)<<4))) = w;
        }
        #pragma unroll
        for (int it = 0; it < 4; ++it) {           // W2s: 128 rows x 128 B
            int e = it * 256 + tid;
            int r = e >> 3; int cb = (e & 7) << 4;
            uint4 w = *(const uint4*)((const char*)(W2t + (size_t)r * H_ + h0) + cb);
            *(uint4*)(W2s + r*128 + (cb ^ ((r&7)<<4))) = w;
        }
        __syncthreads();

        // GEMM1: (16m x 64h) per wave, K=128
        f32x4 acc1[4];
        #pragma unroll
        for (int i = 0; i < 4; ++i) acc1[i] = (f32x4){0.f,0.f,0.f,0.f};
        #pragma unroll
        for (int kk = 0; kk < 4; ++kk) {
            int kb = kk*64 + lh*16;
            int ra = wv*16 + lr;
            bf16x8 a = *(bf16x8*)(Xs + ra*256 + (kb ^ ((ra&7)<<4)));
            #pragma unroll
            for (int nf = 0; nf < 4; ++nf) {
                int rb = nf*16 + lr;
                bf16x8 b = *(bf16x8*)(W1s + rb*256 + (kb ^ ((rb&7)<<4)));
                acc1[nf] = __builtin_amdgcn_mfma_f32_16x16x32_bf16(a, b, acc1[nf], 0, 0, 0);
            }
        }
        // bias + GELU -> Hs (bf16, swizzled)
        #pragma unroll
        for (int nf = 0; nf < 4; ++nf) {
            int col = nf*16 + lr;
            float bias = b1[h0 + col];
            #pragma unroll
            for (int j = 0; j < 4; ++j) {
                int row = wv*16 + lh*4 + j;
                float g = gelu_tanh(acc1[nf][j] + bias);
                *(ushort*)(Hs + row*128 + ((col*2) ^ ((row&7)<<4))) = f2bf(g);
            }
        }
        __syncthreads();

        // GEMM2 accumulate: (16m x 128c) per wave, K=64 (this chunk)
        #pragma unroll
        for (int kk = 0; kk < 2; ++kk) {
            int kb = kk*64 + lh*16;
            int ra = wv*16 + lr;
            bf16x8 a = *(bf16x8*)(Hs + ra*128 + (kb ^ ((ra&7)<<4)));
            #pragma unroll
            for (int nf = 0; nf < 8; ++nf) {
                int rb = nf*16 + lr;
                bf16x8 b = *(bf16x8*)(W2s + rb*128 + (kb ^ ((rb&7)<<4)));
                acc2[nf] = __builtin_amdgcn_mfma_f32_16x16x32_bf16(a, b, acc2[nf], 0, 0, 0);
            }
        }
    }

    // epilogue: BN + residual (fp32 exact base)
    #pragma unroll
    for (int nf = 0; nf < 8; ++nf) {
        int col = nf*16 + lr;
        float s = bns[col], bb = bnb[col];
        #pragma unroll
        for (int j = 0; j < 4; ++j) {
            int row = m0 + wv*16 + lh*4 + j;
            size_t o = (size_t)row * C_ + col;
            xout[o] = xin[o] + acc2[nf][j] * s + bb;
        }
    }
}

// ---------------- vfr linear: x += pe (in place), t = bf16(x @ Wv) ----------------
__global__ __launch_bounds__(256, 2) void vfr_gemm_kernel(
    float* __restrict__ x, const float* __restrict__ pe,
    const ushort* __restrict__ Wvt,   // [cout][k] bf16
    ushort* __restrict__ tout)
{
    __shared__ __attribute__((aligned(16))) char lds[16384 + 32768];
    char* Xs = lds;            // [64][128 bf16] 256 B rows
    char* Ws = lds + 16384;    // [128][128 bf16] 256 B rows

    const int tid  = threadIdx.x;
    const int m0   = blockIdx.x * TM;
    const int wv   = tid >> 6;
    const int lane = tid & 63;
    const int lr   = lane & 15;
    const int lh   = lane >> 4;

    // stage X+pe, write xp back, bf16 to LDS
    #pragma unroll
    for (int it = 0; it < 4; ++it) {
        int idx = it * 2048 + tid * 8;
        int r = idx >> 7, c = idx & 127;
        size_t go = (size_t)(m0 + r) * C_ + c;
        float4 a0 = *(const float4*)(x + go);
        float4 a1 = *(const float4*)(x + go + 4);
        float4 p0 = *(const float4*)(pe + go);
        float4 p1 = *(const float4*)(pe + go + 4);
        a0.x += p0.x; a0.y += p0.y; a0.z += p0.z; a0.w += p0.w;
        a1.x += p1.x; a1.y += p1.y; a1.z += p1.z; a1.w += p1.w;
        *(float4*)(x + go)     = a0;
        *(float4*)(x + go + 4) = a1;
        bf16x8 pk;
        pk[0]=(short)f2bf(a0.x); pk[1]=(short)f2bf(a0.y);
        pk[2]=(short)f2bf(a0.z); pk[3]=(short)f2bf(a0.w);
        pk[4]=(short)f2bf(a1.x); pk[5]=(short)f2bf(a1.y);
        pk[6]=(short)f2bf(a1.z); pk[7]=(short)f2bf(a1.w);
        *(bf16x8*)(Xs + r*256 + ((c*2) ^ ((r&7)<<4))) = pk;
    }
    // stage Wv (full 128x128)
    #pragma unroll
    for (int it = 0; it < 8; ++it) {
        int e = it * 256 + tid;
        int r = e >> 4; int cb = (e & 15) << 4;
        uint4 w = *(const uint4*)((const char*)(Wvt + (size_t)r * C_) + cb);
        *(uint4*)(Ws + r*256 + (cb ^ ((r&7)<<4))) = w;
    }
    __syncthreads();

    f32x4 acc[8];
    #pragma unroll
    for (int i = 0; i < 8; ++i) acc[i] = (f32x4){0.f,0.f,0.f,0.f};
    #pragma unroll
    for (int kk = 0; kk < 4; ++kk) {
        int kb = kk*64 + lh*16;
        int ra = wv*16 + lr;
        bf16x8 a = *(bf16x8*)(Xs + ra*256 + (kb ^ ((ra&7)<<4)));
        #pragma unroll
        for (int nf = 0; nf < 8; ++nf) {
            int rb = nf*16 + lr;
            bf16x8 b = *(bf16x8*)(Ws + rb*256 + (kb ^ ((rb&7)<<4)));
            acc[nf] = __builtin_amdgcn_mfma_f32_16x16x32_bf16(a, b, acc[nf], 0, 0, 0);
        }
    }
    #pragma unroll
    for (int nf = 0; nf < 8; ++nf) {
        int col = nf*16 + lr;
        #pragma unroll
        for (int j = 0; j < 4; ++j) {
            int row = m0 + wv*16 + lh*4 + j;
            tout[(size_t)row * C_ + col] = f2bf(acc[nf][j]);
        }
    }
}

// ---------------- vfr gather: x += BN(max_k t[knn] - t) ----------------
__global__ __launch_bounds__(256) void vfr_gather_kernel(
    float* __restrict__ x, const ushort* __restrict__ t,
    const int* __restrict__ knn,
    const float* __restrict__ s, const float* __restrict__ bb)
{
    const int wv   = threadIdx.x >> 6;
    const int lane = threadIdx.x & 63;
    const int p = blockIdx.x * 4 + wv;          // point id 0..63999
    const int b = p / N_;
    const int base = b * N_;
    const int* kp = knn + (size_t)p * K_;
    const uint* trow = (const uint*)t;          // 64 dwords per row

    uint cen = trow[(size_t)p * 64 + lane];
    float c0 = bf2f((ushort)(cen & 0xffffu));
    float c1 = bf2f((ushort)(cen >> 16));
    float m0v = -INFINITY, m1v = -INFINITY;
    #pragma unroll
    for (int k = 0; k < K_; ++k) {
        int idx = kp[k];
        uint g = trow[(size_t)(base + idx) * 64 + lane];
        m0v = fmaxf(m0v, bf2f((ushort)(g & 0xffffu)));
        m1v = fmaxf(m1v, bf2f((ushort)(g >> 16)));
    }
    m0v -= c0; m1v -= c1;

    int c = lane * 2;
    float2 sv = *(const float2*)(s + c);
    float2 bv = *(const float2*)(bb + c);
    size_t o = (size_t)p * C_ + c;
    float2 xv = *(const float2*)(x + o);
    xv.x += m0v * sv.x + bv.x;
    xv.y += m1v * sv.y + bv.y;
    *(float2*)(x + o) = xv;
}

extern "C" void kernel_launch(void* const* d_in, const int* in_sizes, int n_in,
                              void* d_out, int out_size, void* d_ws, size_t ws_size,
                              hipStream_t stream) {
    const float* x      = (const float*)d_in[0];
    const float* pe     = (const float*)d_in[1];
    const int*   knn    = (const int*)d_in[2];
    const float* mlp_W1 = (const float*)d_in[3];
    const float* mlp_b1 = (const float*)d_in[4];
    const float* mlp_W2 = (const float*)d_in[5];
    const float* mlp_g  = (const float*)d_in[6];
    const float* mlp_be = (const float*)d_in[7];
    const float* mlp_m  = (const float*)d_in[8];
    const float* mlp_v  = (const float*)d_in[9];
    const float* vfr_W  = (const float*)d_in[10];
    const float* vfr_g  = (const float*)d_in[11];
    const float* vfr_be = (const float*)d_in[12];
    const float* vfr_m  = (const float*)d_in[13];
    const float* vfr_v  = (const float*)d_in[14];
    const float* ffn_W1 = (const float*)d_in[15];
    const float* ffn_b1 = (const float*)d_in[16];
    const float* ffn_W2 = (const float*)d_in[17];
    const float* ffn_g  = (const float*)d_in[18];
    const float* ffn_be = (const float*)d_in[19];
    const float* ffn_m  = (const float*)d_in[20];
    const float* ffn_v  = (const float*)d_in[21];
    float* out = (float*)d_out;

    char* ws = (char*)d_ws;
    ushort* tbuf = (ushort*)ws;  ws += (size_t)R_ * C_ * 2;       // 16.4 MB
    ushort* w1t  = (ushort*)ws;  ws += (size_t)5 * H_ * C_ * 2;
    ushort* w2t  = (ushort*)ws;  ws += (size_t)5 * C_ * H_ * 2;
    ushort* wvt  = (ushort*)ws;  ws += (size_t)D_ * C_ * C_ * 2;
    float*  b1a  = (float*)ws;   ws += (size_t)5 * H_ * 4;
    float*  fs   = (float*)ws;   ws += (size_t)5 * C_ * 4;
    float*  fb   = (float*)ws;   ws += (size_t)5 * C_ * 4;
    float*  vs   = (float*)ws;   ws += (size_t)D_ * C_ * 4;
    float*  vb   = (float*)ws;   ws += (size_t)D_ * C_ * 4;

    const int prep_items = 2*(5*H_*C_) + D_*C_*C_ + 5*H_ + 5*C_ + D_*C_;
    prep_kernel<<<(prep_items + 255) / 256, 256, 0, stream>>>(
        mlp_W1, mlp_b1, mlp_W2, mlp_g, mlp_be, mlp_m, mlp_v,
        vfr_W, vfr_g, vfr_be, vfr_m, vfr_v,
        ffn_W1, ffn_b1, ffn_W2, ffn_g, ffn_be, ffn_m, ffn_v,
        w1t, w2t, wvt, b1a, fs, fb, vs, vb);

    // x1 = x0 + FFN_mlp(x0)  -> out
    ffn_kernel<<<R_/TM, 256, 0, stream>>>(x, out, w1t, w2t, b1a, fs, fb);

    for (int d = 0; d < D_; ++d) {
        vfr_gemm_kernel<<<R_/TM, 256, 0, stream>>>(
            out, pe, wvt + (size_t)d * C_ * C_, tbuf);
        vfr_gather_kernel<<<R_/4, 256, 0, stream>>>(
            out, tbuf, knn, vs + d * C_, vb + d * C_);
        ffn_kernel<<<R_/TM, 256, 0, stream>>>(
            out, out,
            w1t + (size_t)(d+1) * H_ * C_, w2t + (size_t)(d+1) * C_ * H_,
            b1a + (d+1) * H_, fs + (d+1) * C_, fb + (d+1) * C_);
    }
}

// Round 2
// 379.169 us; speedup vs baseline: 1.4068x; 1.4068x over previous
//
#include <hip/hip_runtime.h>
#include <hip/hip_bf16.h>

typedef __attribute__((ext_vector_type(8))) short bf16x8;
typedef __attribute__((ext_vector_type(4))) float f32x4;

#define B_ 4
#define N_ 16000
#define C_ 128
#define K_ 16
#define D_ 4
#define H_ 512
#define R_ (B_*N_)      // 64000 rows
#define TM 64           // rows per block tile
#define EPSV 1e-5f

__device__ __forceinline__ ushort f2bf(float f) {
    uint32_t b = __builtin_bit_cast(uint32_t, f);
    b += 0x7fffu + ((b >> 16) & 1u);   // RNE
    return (ushort)(b >> 16);
}
__device__ __forceinline__ float bf2f(ushort u) {
    return __builtin_bit_cast(float, (uint32_t)u << 16);
}
// gelu_tanh(v) = v * sigmoid(2u), u = 0.79788456*(v + 0.044715 v^3)
// exp-based: ~8 VALU ops, exact limits at +/-inf.
__device__ __forceinline__ float gelu_fast(float v) {
    float v2 = v * v;
    float u = v * fmaf(0.0356774081f, v2, 0.7978845608f);   // c1*a*v^2 + c1
    float e = __expf(-2.0f * u);
    return v * __builtin_amdgcn_rcpf(1.0f + e);
}
// async global->LDS, 16B per lane; lds base must be wave-uniform
__device__ __forceinline__ void gll16(const void* g, void* l) {
    __builtin_amdgcn_global_load_lds(
        (__attribute__((address_space(1))) void*)g,
        (__attribute__((address_space(3))) void*)l, 16, 0, 0);
}

// ---------------- prep: transpose weights to Bt[n][k] bf16, fold BN ----------------
__global__ void prep_kernel(
    const float* __restrict__ mlp_W1, const float* __restrict__ mlp_b1,
    const float* __restrict__ mlp_W2, const float* __restrict__ mlp_g,
    const float* __restrict__ mlp_be, const float* __restrict__ mlp_m,
    const float* __restrict__ mlp_v,
    const float* __restrict__ vfr_W, const float* __restrict__ vfr_g,
    const float* __restrict__ vfr_be, const float* __restrict__ vfr_m,
    const float* __restrict__ vfr_v,
    const float* __restrict__ ffn_W1, const float* __restrict__ ffn_b1,
    const float* __restrict__ ffn_W2, const float* __restrict__ ffn_g,
    const float* __restrict__ ffn_be, const float* __restrict__ ffn_m,
    const float* __restrict__ ffn_v,
    ushort* __restrict__ w1t, ushort* __restrict__ w2t, ushort* __restrict__ wvt,
    float* __restrict__ b1a, float* __restrict__ fs, float* __restrict__ fb,
    float* __restrict__ vs, float* __restrict__ vb)
{
    int i = blockIdx.x * 256 + threadIdx.x;
    const int NW = 5 * H_ * C_;   // 327680
    if (i < NW) {                 // w1t[f][h][c] = W1_f[c][h]
        int f = i / (H_*C_), e = i % (H_*C_);
        int h = e / C_, c = e % C_;
        const float* src = (f == 0) ? mlp_W1 : ffn_W1 + (size_t)(f-1)*C_*H_;
        w1t[i] = f2bf(src[(size_t)c*H_ + h]);
        return;
    }
    i -= NW;
    if (i < NW) {                 // w2t[f][c][h] = W2_f[h][c]
        int f = i / (H_*C_), e = i % (H_*C_);
        int c = e / H_, h = e % H_;
        const float* src = (f == 0) ? mlp_W2 : ffn_W2 + (size_t)(f-1)*H_*C_;
        w2t[i] = f2bf(src[(size_t)h*C_ + c]);
        return;
    }
    i -= NW;
    if (i < D_*C_*C_) {           // wvt[d][cout][k] = W[d][k][cout]
        int d = i / (C_*C_), e = i % (C_*C_);
        int co = e / C_, k = e % C_;
        wvt[i] = f2bf(vfr_W[(size_t)d*C_*C_ + (size_t)k*C_ + co]);
        return;
    }
    i -= D_*C_*C_;
    if (i < 5*H_) {               // biases
        int f = i / H_, h = i % H_;
        b1a[i] = (f == 0) ? mlp_b1[h] : ffn_b1[(f-1)*H_ + h];
        return;
    }
    i -= 5*H_;
    if (i < 5*C_) {               // ffn BN: y*s + b
        int f = i / C_, c = i % C_;
        float g  = (f==0) ? mlp_g[c]  : ffn_g[(f-1)*C_ + c];
        float be = (f==0) ? mlp_be[c] : ffn_be[(f-1)*C_ + c];
        float m  = (f==0) ? mlp_m[c]  : ffn_m[(f-1)*C_ + c];
        float v  = (f==0) ? mlp_v[c]  : ffn_v[(f-1)*C_ + c];
        float s = g * rsqrtf(v + EPSV);
        fs[i] = s; fb[i] = be - m * s;
        return;
    }
    i -= 5*C_;
    if (i < D_*C_) {              // vfr BN
        float s = vfr_g[i] * rsqrtf(vfr_v[i] + EPSV);
        vs[i] = s; vb[i] = vfr_be[i] - vfr_m[i] * s;
    }
}

// ---------------- fused FFN: x_out = x_in + BN(gelu(x@W1+b1)@W2) ----------------
// 64-row tile per block, 4 waves (16 rows each); X A-frags in registers;
// W tiles staged async via global_load_lds with pre-swizzled source;
// Hs is wave-local (no barrier between GEMM1 and GEMM2). LDS 40KB -> 4 blocks/CU.
__global__ __launch_bounds__(256, 4) void ffn_kernel(
    const float* __restrict__ xin, float* __restrict__ xout,
    const ushort* __restrict__ W1t,   // [H][C] bf16 (Bt for GEMM1)
    const ushort* __restrict__ W2t,   // [C][H] bf16 (Bt for GEMM2)
    const float* __restrict__ b1,
    const float* __restrict__ bns, const float* __restrict__ bnb)
{
    __shared__ __attribute__((aligned(16))) char lds[16384 + 16384 + 8192];
    char* W1s = lds;           // [64 h][128 c] bf16, 256 B rows, swizzled
    char* W2s = lds + 16384;   // [128 c][64 h] bf16, 128 B rows, swizzled
    char* Hs  = lds + 32768;   // [64 m][64 h] bf16, 128 B rows, swizzled

    const int tid  = threadIdx.x;
    const int m0   = blockIdx.x * TM;
    const int wv   = tid >> 6;
    const int lane = tid & 63;
    const int lr   = lane & 15;
    const int lh   = lane >> 4;    // 0..3

    // X A-fragments in registers: row m0+wv*16+lr, k = kk*32 + lh*8 + j
    bf16x8 xa[4];
    {
        const float* xrow = xin + (size_t)(m0 + wv*16 + lr) * C_ + lh*8;
        #pragma unroll
        for (int kk = 0; kk < 4; ++kk) {
            float4 v0 = *(const float4*)(xrow + kk*32);
            float4 v1 = *(const float4*)(xrow + kk*32 + 4);
            bf16x8 pk;
            pk[0]=(short)f2bf(v0.x); pk[1]=(short)f2bf(v0.y);
            pk[2]=(short)f2bf(v0.z); pk[3]=(short)f2bf(v0.w);
            pk[4]=(short)f2bf(v1.x); pk[5]=(short)f2bf(v1.y);
            pk[6]=(short)f2bf(v1.z); pk[7]=(short)f2bf(v1.w);
            xa[kk] = pk;
        }
    }

    f32x4 acc2[8];
    #pragma unroll
    for (int i = 0; i < 8; ++i) acc2[i] = (f32x4){0.f,0.f,0.f,0.f};

    const int q16 = lane >> 4, l16 = lane & 15;   // W1s staging geometry
    const int q8  = lane >> 3, l8  = lane & 7;    // W2s staging geometry

    for (int hc = 0; hc < 8; ++hc) {
        const int h0 = hc * 64;
        __syncthreads();   // all waves done reading W tiles of previous chunk

        // W1s: wave quarter = rows wv*16 + i*4 + q16, 16B at cb = l16*16
        #pragma unroll
        for (int i = 0; i < 4; ++i) {
            int row = wv*16 + i*4 + q16;
            int cb  = l16*16;
            const char* src = (const char*)(W1t + (size_t)(h0 + row) * C_)
                            + (cb ^ ((row&7)<<4));
            gll16(src, W1s + wv*4096 + i*1024);
        }
        // W2s: wave quarter = rows wv*32 + i*8 + q8, 16B at cb = l8*16
        #pragma unroll
        for (int i = 0; i < 4; ++i) {
            int row = wv*32 + i*8 + q8;
            int cb  = l8*16;
            const char* src = (const char*)(W2t + (size_t)row * H_ + h0)
                            + (cb ^ ((row&7)<<4));
            gll16(src, W2s + wv*4096 + i*1024);
        }
        __syncthreads();   // vmcnt(0) drain: W tiles visible to all waves

        // GEMM1: (16m x 64h) per wave, K=128, A from registers
        f32x4 acc1[4];
        #pragma unroll
        for (int i = 0; i < 4; ++i) acc1[i] = (f32x4){0.f,0.f,0.f,0.f};
        #pragma unroll
        for (int kk = 0; kk < 4; ++kk) {
            int kb = kk*64 + lh*16;
            #pragma unroll
            for (int nf = 0; nf < 4; ++nf) {
                int rb = nf*16 + lr;
                bf16x8 b = *(bf16x8*)(W1s + rb*256 + (kb ^ ((rb&7)<<4)));
                acc1[nf] = __builtin_amdgcn_mfma_f32_16x16x32_bf16(xa[kk], b, acc1[nf], 0, 0, 0);
            }
        }
        // bias + GELU -> Hs (wave-local rows, no barrier needed)
        #pragma unroll
        for (int nf = 0; nf < 4; ++nf) {
            int col = nf*16 + lr;
            float bias = b1[h0 + col];
            #pragma unroll
            for (int j = 0; j < 4; ++j) {
                int row = wv*16 + lh*4 + j;
                float g = gelu_fast(acc1[nf][j] + bias);
                *(ushort*)(Hs + row*128 + ((col*2) ^ ((row&7)<<4))) = f2bf(g);
            }
        }
        // GEMM2 accumulate: (16m x 128c) per wave, K=64 (this chunk)
        #pragma unroll
        for (int kk = 0; kk < 2; ++kk) {
            int kb = kk*64 + lh*16;
            int ra = wv*16 + lr;
            bf16x8 a = *(bf16x8*)(Hs + ra*128 + (kb ^ ((ra&7)<<4)));
            #pragma unroll
            for (int nf = 0; nf < 8; ++nf) {
                int rb = nf*16 + lr;
                bf16x8 b = *(bf16x8*)(W2s + rb*128 + (kb ^ ((rb&7)<<4)));
                acc2[nf] = __builtin_amdgcn_mfma_f32_16x16x32_bf16(a, b, acc2[nf], 0, 0, 0);
            }
        }
    }

    // epilogue: BN + residual (fp32 exact base)
    #pragma unroll
    for (int nf = 0; nf < 8; ++nf) {
        int col = nf*16 + lr;
        float s = bns[col], bb = bnb[col];
        #pragma unroll
        for (int j = 0; j < 4; ++j) {
            int row = m0 + wv*16 + lh*4 + j;
            size_t o = (size_t)row * C_ + col;
            xout[o] = xin[o] + acc2[nf][j] * s + bb;
        }
    }
}

// ---------------- vfr linear: x += pe (in place), t = bf16(x @ Wv) ----------------
__global__ __launch_bounds__(256, 2) void vfr_gemm_kernel(
    float* __restrict__ x, const float* __restrict__ pe,
    const ushort* __restrict__ Wvt,   // [cout][k] bf16
    ushort* __restrict__ tout)
{
    __shared__ __attribute__((aligned(16))) char lds[16384 + 32768];
    char* Xs = lds;            // [64][128 bf16] 256 B rows
    char* Ws = lds + 16384;    // [128][128 bf16] 256 B rows

    const int tid  = threadIdx.x;
    const int m0   = blockIdx.x * TM;
    const int wv   = tid >> 6;
    const int lane = tid & 63;
    const int lr   = lane & 15;
    const int lh   = lane >> 4;

    // stage X+pe, write xp back, bf16 to LDS
    #pragma unroll
    for (int it = 0; it < 4; ++it) {
        int idx = it * 2048 + tid * 8;
        int r = idx >> 7, c = idx & 127;
        size_t go = (size_t)(m0 + r) * C_ + c;
        float4 a0 = *(const float4*)(x + go);
        float4 a1 = *(const float4*)(x + go + 4);
        float4 p0 = *(const float4*)(pe + go);
        float4 p1 = *(const float4*)(pe + go + 4);
        a0.x += p0.x; a0.y += p0.y; a0.z += p0.z; a0.w += p0.w;
        a1.x += p1.x; a1.y += p1.y; a1.z += p1.z; a1.w += p1.w;
        *(float4*)(x + go)     = a0;
        *(float4*)(x + go + 4) = a1;
        bf16x8 pk;
        pk[0]=(short)f2bf(a0.x); pk[1]=(short)f2bf(a0.y);
        pk[2]=(short)f2bf(a0.z); pk[3]=(short)f2bf(a0.w);
        pk[4]=(short)f2bf(a1.x); pk[5]=(short)f2bf(a1.y);
        pk[6]=(short)f2bf(a1.z); pk[7]=(short)f2bf(a1.w);
        *(bf16x8*)(Xs + r*256 + ((c*2) ^ ((r&7)<<4))) = pk;
    }
    // stage Wv (full 128x128)
    #pragma unroll
    for (int it = 0; it < 8; ++it) {
        int e = it * 256 + tid;
        int r = e >> 4; int cb = (e & 15) << 4;
        uint4 w = *(const uint4*)((const char*)(Wvt + (size_t)r * C_) + cb);
        *(uint4*)(Ws + r*256 + (cb ^ ((r&7)<<4))) = w;
    }
    __syncthreads();

    f32x4 acc[8];
    #pragma unroll
    for (int i = 0; i < 8; ++i) acc[i] = (f32x4){0.f,0.f,0.f,0.f};
    #pragma unroll
    for (int kk = 0; kk < 4; ++kk) {
        int kb = kk*64 + lh*16;
        int ra = wv*16 + lr;
        bf16x8 a = *(bf16x8*)(Xs + ra*256 + (kb ^ ((ra&7)<<4)));
        #pragma unroll
        for (int nf = 0; nf < 8; ++nf) {
            int rb = nf*16 + lr;
            bf16x8 b = *(bf16x8*)(Ws + rb*256 + (kb ^ ((rb&7)<<4)));
            acc[nf] = __builtin_amdgcn_mfma_f32_16x16x32_bf16(a, b, acc[nf], 0, 0, 0);
        }
    }
    #pragma unroll
    for (int nf = 0; nf < 8; ++nf) {
        int col = nf*16 + lr;
        #pragma unroll
        for (int j = 0; j < 4; ++j) {
            int row = m0 + wv*16 + lh*4 + j;
            tout[(size_t)row * C_ + col] = f2bf(acc[nf][j]);
        }
    }
}

// ---------------- vfr gather: x += BN(max_k t[knn] - t) ----------------
__global__ __launch_bounds__(256) void vfr_gather_kernel(
    float* __restrict__ x, const ushort* __restrict__ t,
    const int* __restrict__ knn,
    const float* __restrict__ s, const float* __restrict__ bb)
{
    const int wv   = threadIdx.x >> 6;
    const int lane = threadIdx.x & 63;
    const int p = blockIdx.x * 4 + wv;          // point id 0..63999
    const int b = p / N_;
    const int base = b * N_;
    const int* kp = knn + (size_t)p * K_;
    const uint* trow = (const uint*)t;          // 64 dwords per row

    uint cen = trow[(size_t)p * 64 + lane];
    float c0 = bf2f((ushort)(cen & 0xffffu));
    float c1 = bf2f((ushort)(cen >> 16));
    float m0v = -INFINITY, m1v = -INFINITY;
    #pragma unroll
    for (int k = 0; k < K_; ++k) {
        int idx = kp[k];
        uint g = trow[(size_t)(base + idx) * 64 + lane];
        m0v = fmaxf(m0v, bf2f((ushort)(g & 0xffffu)));
        m1v = fmaxf(m1v, bf2f((ushort)(g >> 16)));
    }
    m0v -= c0; m1v -= c1;

    int c = lane * 2;
    float2 sv = *(const float2*)(s + c);
    float2 bv = *(const float2*)(bb + c);
    size_t o = (size_t)p * C_ + c;
    float2 xv = *(const float2*)(x + o);
    xv.x += m0v * sv.x + bv.x;
    xv.y += m1v * sv.y + bv.y;
    *(float2*)(x + o) = xv;
}

extern "C" void kernel_launch(void* const* d_in, const int* in_sizes, int n_in,
                              void* d_out, int out_size, void* d_ws, size_t ws_size,
                              hipStream_t stream) {
    const float* x      = (const float*)d_in[0];
    const float* pe     = (const float*)d_in[1];
    const int*   knn    = (const int*)d_in[2];
    const float* mlp_W1 = (const float*)d_in[3];
    const float* mlp_b1 = (const float*)d_in[4];
    const float* mlp_W2 = (const float*)d_in[5];
    const float* mlp_g  = (const float*)d_in[6];
    const float* mlp_be = (const float*)d_in[7];
    const float* mlp_m  = (const float*)d_in[8];
    const float* mlp_v  = (const float*)d_in[9];
    const float* vfr_W  = (const float*)d_in[10];
    const float* vfr_g  = (const float*)d_in[11];
    const float* vfr_be = (const float*)d_in[12];
    const float* vfr_m  = (const float*)d_in[13];
    const float* vfr_v  = (const float*)d_in[14];
    const float* ffn_W1 = (const float*)d_in[15];
    const float* ffn_b1 = (const float*)d_in[16];
    const float* ffn_W2 = (const float*)d_in[17];
    const float* ffn_g  = (const float*)d_in[18];
    const float* ffn_be = (const float*)d_in[19];
    const float* ffn_m  = (const float*)d_in[20];
    const float* ffn_v  = (const float*)d_in[21];
    float* out = (float*)d_out;

    char* ws = (char*)d_ws;
    ushort* tbuf = (ushort*)ws;  ws += (size_t)R_ * C_ * 2;       // 16.4 MB
    ushort* w1t  = (ushort*)ws;  ws += (size_t)5 * H_ * C_ * 2;
    ushort* w2t  = (ushort*)ws;  ws += (size_t)5 * C_ * H_ * 2;
    ushort* wvt  = (ushort*)ws;  ws += (size_t)D_ * C_ * C_ * 2;
    float*  b1a  = (float*)ws;   ws += (size_t)5 * H_ * 4;
    float*  fs   = (float*)ws;   ws += (size_t)5 * C_ * 4;
    float*  fb   = (float*)ws;   ws += (size_t)5 * C_ * 4;
    float*  vs   = (float*)ws;   ws += (size_t)D_ * C_ * 4;
    float*  vb   = (float*)ws;   ws += (size_t)D_ * C_ * 4;

    const int prep_items = 2*(5*H_*C_) + D_*C_*C_ + 5*H_ + 5*C_ + D_*C_;
    prep_kernel<<<(prep_items + 255) / 256, 256, 0, stream>>>(
        mlp_W1, mlp_b1, mlp_W2, mlp_g, mlp_be, mlp_m, mlp_v,
        vfr_W, vfr_g, vfr_be, vfr_m, vfr_v,
        ffn_W1, ffn_b1, ffn_W2, ffn_g, ffn_be, ffn_m, ffn_v,
        w1t, w2t, wvt, b1a, fs, fb, vs, vb);

    // x1 = x0 + FFN_mlp(x0)  -> out
    ffn_kernel<<<R_/TM, 256, 0, stream>>>(x, out, w1t, w2t, b1a, fs, fb);

    for (int d = 0; d < D_; ++d) {
        vfr_gemm_kernel<<<R_/TM, 256, 0, stream>>>(
            out, pe, wvt + (size_t)d * C_ * C_, tbuf);
        vfr_gather_kernel<<<R_/4, 256, 0, stream>>>(
            out, tbuf, knn, vs + d * C_, vb + d * C_);
        ffn_kernel<<<R_/TM, 256, 0, stream>>>(
            out, out,
            w1t + (size_t)(d+1) * H_ * C_, w2t + (size_t)(d+1) * C_ * H_,
            b1a + (d+1) * H_, fs + (d+1) * C_, fb + (d+1) * C_);
    }
}

// Round 3
// 366.244 us; speedup vs baseline: 1.4564x; 1.0353x over previous
//
#include <hip/hip_runtime.h>
#include <hip/hip_bf16.h>

typedef __attribute__((ext_vector_type(8))) short bf16x8;
typedef __attribute__((ext_vector_type(4))) short bf16x4;
typedef __attribute__((ext_vector_type(4))) float f32x4;

#define B_ 4
#define N_ 16000
#define C_ 128
#define K_ 16
#define D_ 4
#define H_ 512
#define R_ (B_*N_)      // 64000 rows
#define EPSV 1e-5f

__device__ __forceinline__ ushort f2bf(float f) {
    uint32_t b = __builtin_bit_cast(uint32_t, f);
    b += 0x7fffu + ((b >> 16) & 1u);   // RNE
    return (ushort)(b >> 16);
}
__device__ __forceinline__ float bf2f(ushort u) {
    return __builtin_bit_cast(float, (uint32_t)u << 16);
}
// gelu_tanh(v) = v * sigmoid(2u), u = 0.79788456*(v + 0.044715 v^3)
__device__ __forceinline__ float gelu_fast(float v) {
    float v2 = v * v;
    float u = v * fmaf(0.0356774081f, v2, 0.7978845608f);
    float e = __expf(-2.0f * u);
    return v * __builtin_amdgcn_rcpf(1.0f + e);
}
// async global->LDS, 16B per lane; lds base must be wave-uniform
__device__ __forceinline__ void gll16(const void* g, void* l) {
    __builtin_amdgcn_global_load_lds(
        (__attribute__((address_space(1))) void*)g,
        (__attribute__((address_space(3))) void*)l, 16, 0, 0);
}

// ---------------- prep: transpose weights bf16, fold BN ----------------
// w2p is sigma-permuted along h (within each 32-h block): slot s=8*lam+j
// holds h = 4*lam + (j&3) + 16*(j>>2), so GEMM2's A-operand can be built
// register-locally from swapped-GEMM1 accumulator fragments.
__global__ void prep_kernel(
    const float* __restrict__ mlp_W1, const float* __restrict__ mlp_b1,
    const float* __restrict__ mlp_W2, const float* __restrict__ mlp_g,
    const float* __restrict__ mlp_be, const float* __restrict__ mlp_m,
    const float* __restrict__ mlp_v,
    const float* __restrict__ vfr_W, const float* __restrict__ vfr_g,
    const float* __restrict__ vfr_be, const float* __restrict__ vfr_m,
    const float* __restrict__ vfr_v,
    const float* __restrict__ ffn_W1, const float* __restrict__ ffn_b1,
    const float* __restrict__ ffn_W2, const float* __restrict__ ffn_g,
    const float* __restrict__ ffn_be, const float* __restrict__ ffn_m,
    const float* __restrict__ ffn_v,
    ushort* __restrict__ w1t, ushort* __restrict__ w2p, ushort* __restrict__ wvt,
    float* __restrict__ b1a, float* __restrict__ fs, float* __restrict__ fb,
    float* __restrict__ vs, float* __restrict__ vb)
{
    int i = blockIdx.x * 256 + threadIdx.x;
    const int NW = 5 * H_ * C_;   // 327680
    if (i < NW) {                 // w1t[f][h][c] = W1_f[c][h]
        int f = i / (H_*C_), e = i % (H_*C_);
        int h = e / C_, c = e % C_;
        const float* src = (f == 0) ? mlp_W1 : ffn_W1 + (size_t)(f-1)*C_*H_;
        w1t[i] = f2bf(src[(size_t)c*H_ + h]);
        return;
    }
    i -= NW;
    if (i < NW) {                 // w2p[f][c][p] = W2_f[sigma(p)][c]
        int f = i / (H_*C_), e = i % (H_*C_);
        int c = e / H_, p = e % H_;
        int s = p & 31, lam = s >> 3, j = s & 7;
        int h = (p & ~31) + lam*4 + (j & 3) + ((j >> 2) << 4);
        const float* src = (f == 0) ? mlp_W2 : ffn_W2 + (size_t)(f-1)*H_*C_;
        w2p[i] = f2bf(src[(size_t)h*C_ + c]);
        return;
    }
    i -= NW;
    if (i < D_*C_*C_) {           // wvt[d][cout][k] = W[d][k][cout]
        int d = i / (C_*C_), e = i % (C_*C_);
        int co = e / C_, k = e % C_;
        wvt[i] = f2bf(vfr_W[(size_t)d*C_*C_ + (size_t)k*C_ + co]);
        return;
    }
    i -= D_*C_*C_;
    if (i < 5*H_) {               // biases
        int f = i / H_, h = i % H_;
        b1a[i] = (f == 0) ? mlp_b1[h] : ffn_b1[(f-1)*H_ + h];
        return;
    }
    i -= 5*H_;
    if (i < 5*C_) {               // ffn BN: y*s + b
        int f = i / C_, c = i % C_;
        float g  = (f==0) ? mlp_g[c]  : ffn_g[(f-1)*C_ + c];
        float be = (f==0) ? mlp_be[c] : ffn_be[(f-1)*C_ + c];
        float m  = (f==0) ? mlp_m[c]  : ffn_m[(f-1)*C_ + c];
        float v  = (f==0) ? mlp_v[c]  : ffn_v[(f-1)*C_ + c];
        float s = g * rsqrtf(v + EPSV);
        fs[i] = s; fb[i] = be - m * s;
        return;
    }
    i -= 5*C_;
    if (i < D_*C_) {              // vfr BN
        float s = vfr_g[i] * rsqrtf(vfr_v[i] + EPSV);
        vs[i] = s; vb[i] = vfr_be[i] - vfr_m[i] * s;
    }
}

// ---------------- fused FFN: x_out = x_in [+ pe] + BN(gelu(x@W1+b1)@W2) ----------
// TM=128 rows/block, 512 threads (8 waves, 16 rows each). X A-frags in regs.
// Double-buffered W tiles (2 x 32KB), staged one chunk ahead via global_load_lds:
// the barrier's vmcnt(0) drain is covered by a full compute phase (T3 2-phase).
// GEMM1 operand-swapped (D[h][m]); GEMM2 A built in-register via sigma-permuted W2.
template<bool ADD_PE>
__global__ __launch_bounds__(512, 4) void ffn_kernel(
    const float* __restrict__ xin, float* __restrict__ xout,
    const float* __restrict__ pe,
    const ushort* __restrict__ W1t,   // [H][C] bf16
    const ushort* __restrict__ W2p,   // [C][H] bf16, sigma-permuted in h
    const float* __restrict__ b1,
    const float* __restrict__ bns, const float* __restrict__ bnb)
{
    __shared__ __attribute__((aligned(16))) char lds[65536];  // 2 x (W1s 16K + W2s 16K)

    const int tid  = threadIdx.x;
    const int m0   = blockIdx.x * 128;
    const int wv   = tid >> 6;        // 0..7
    const int lane = tid & 63;
    const int lr   = lane & 15;
    const int lh   = lane >> 4;       // 0..3

    // X A-fragments in registers: row m0+wv*16+lr, k = kk*32 + lh*8 + j
    bf16x8 xa[4];

    // ---- stage chunk hc's W tiles into buffer buf ----
    auto stageW = [&](int hc, int buf) {
        char* base = lds + buf * 32768;
        const int h0 = hc * 64;
        #pragma unroll
        for (int i = 0; i < 2; ++i) {      // W1s: [64 h][256B] swizzled
            int row = i*32 + wv*4 + (lane >> 4);
            int cb  = (lane & 15) * 16;
            const char* src = (const char*)(W1t + (size_t)(h0 + row) * C_)
                            + (cb ^ ((row & 7) << 4));
            gll16(src, base + i*8192 + wv*1024);
        }
        #pragma unroll
        for (int i = 0; i < 2; ++i) {      // W2s: [128 c][128B] swizzled
            int row = i*64 + wv*8 + (lane >> 3);
            int cb  = (lane & 7) * 16;
            const char* src = (const char*)(W2p + (size_t)row * H_ + h0)
                            + (cb ^ ((row & 7) << 4));
            gll16(src, base + 16384 + i*8192 + wv*1024);
        }
    };

    stageW(0, 0);   // prologue prefetch

    {
        const float* xrow = xin + (size_t)(m0 + wv*16 + lr) * C_ + lh*8;
        #pragma unroll
        for (int kk = 0; kk < 4; ++kk) {
            float4 v0 = *(const float4*)(xrow + kk*32);
            float4 v1 = *(const float4*)(xrow + kk*32 + 4);
            bf16x8 pk;
            pk[0]=(short)f2bf(v0.x); pk[1]=(short)f2bf(v0.y);
            pk[2]=(short)f2bf(v0.z); pk[3]=(short)f2bf(v0.w);
            pk[4]=(short)f2bf(v1.x); pk[5]=(short)f2bf(v1.y);
            pk[6]=(short)f2bf(v1.z); pk[7]=(short)f2bf(v1.w);
            xa[kk] = pk;
        }
    }

    f32x4 acc2[8];
    #pragma unroll
    for (int i = 0; i < 8; ++i) acc2[i] = (f32x4){0.f,0.f,0.f,0.f};

    __syncthreads();   // chunk 0 staged (drain covered only by xa loads; once per kernel)

    for (int hc = 0; hc < 8; ++hc) {
        const int h0  = hc * 64;
        const int buf = hc & 1;
        if (hc < 7) stageW(hc + 1, buf ^ 1);   // prefetch next chunk

        char* W1s = lds + buf * 32768;
        char* W2s = W1s + 16384;

        // GEMM1 swapped: acc1[nf] = D[h = nf*16 + lh*4+j][m = lr]
        f32x4 acc1[4];
        #pragma unroll
        for (int i = 0; i < 4; ++i) acc1[i] = (f32x4){0.f,0.f,0.f,0.f};
        #pragma unroll
        for (int kk = 0; kk < 4; ++kk) {
            int kb = kk*64 + lh*16;
            #pragma unroll
            for (int nf = 0; nf < 4; ++nf) {
                int rb = nf*16 + lr;
                bf16x8 w1 = *(bf16x8*)(W1s + rb*256 + (kb ^ ((rb&7)<<4)));
                acc1[nf] = __builtin_amdgcn_mfma_f32_16x16x32_bf16(w1, xa[kk], acc1[nf], 0, 0, 0);
            }
        }
        // bias + GELU -> bf16 A-fragments pa[nf] (h-local = nf*16 + lh*4 + j, m = lr)
        bf16x4 pa[4];
        #pragma unroll
        for (int nf = 0; nf < 4; ++nf) {
            float4 bias = *(const float4*)(b1 + h0 + nf*16 + lh*4);
            bf16x4 p;
            p[0] = (short)f2bf(gelu_fast(acc1[nf][0] + bias.x));
            p[1] = (short)f2bf(gelu_fast(acc1[nf][1] + bias.y));
            p[2] = (short)f2bf(gelu_fast(acc1[nf][2] + bias.z));
            p[3] = (short)f2bf(gelu_fast(acc1[nf][3] + bias.w));
            pa[nf] = p;
        }
        // GEMM2: A = concat(pa[2g], pa[2g+1]) (sigma-slot order), B = permuted W2
        #pragma unroll
        for (int g = 0; g < 2; ++g) {
            bf16x8 af = __builtin_shufflevector(pa[2*g], pa[2*g+1], 0,1,2,3,4,5,6,7);
            int kb = g*64 + lh*16;
            #pragma unroll
            for (int nf = 0; nf < 8; ++nf) {
                int rb = nf*16 + lr;
                bf16x8 w2 = *(bf16x8*)(W2s + rb*128 + (kb ^ ((rb&7)<<4)));
                acc2[nf] = __builtin_amdgcn_mfma_f32_16x16x32_bf16(af, w2, acc2[nf], 0, 0, 0);
            }
        }
        __syncthreads();   // next chunk's loads drained (covered by this compute)
    }

    // epilogue: BN + residual (+ pe) on exact fp32 base
    #pragma unroll
    for (int nf = 0; nf < 8; ++nf) {
        int col = nf*16 + lr;
        float s = bns[col], bb = bnb[col];
        #pragma unroll
        for (int j = 0; j < 4; ++j) {
            int row = m0 + wv*16 + lh*4 + j;
            size_t o = (size_t)row * C_ + col;
            float base = xin[o] + (ADD_PE ? pe[o] : 0.0f);
            xout[o] = base + acc2[nf][j] * s + bb;
        }
    }
}

// ---------------- vfr linear: t = bf16(x @ Wv)  (x already contains pe) --------
__global__ __launch_bounds__(256, 4) void vfr_gemm_kernel(
    const float* __restrict__ x,
    const ushort* __restrict__ Wvt,   // [cout][k] bf16
    ushort* __restrict__ tout)
{
    __shared__ __attribute__((aligned(16))) char Ws[32768];  // [128][256B] swizzled

    const int tid  = threadIdx.x;
    const int m0   = blockIdx.x * 64;
    const int wv   = tid >> 6;
    const int lane = tid & 63;
    const int lr   = lane & 15;
    const int lh   = lane >> 4;

    // stage Wv via global_load_lds (8 rounds x 4KB)
    #pragma unroll
    for (int i = 0; i < 8; ++i) {
        int row = i*16 + wv*4 + (lane >> 4);
        int cb  = (lane & 15) * 16;
        const char* src = (const char*)(Wvt + (size_t)row * C_)
                        + (cb ^ ((row & 7) << 4));
        gll16(src, Ws + i*4096 + wv*1024);
    }

    // X A-frags in registers
    bf16x8 xa[4];
    {
        const float* xrow = x + (size_t)(m0 + wv*16 + lr) * C_ + lh*8;
        #pragma unroll
        for (int kk = 0; kk < 4; ++kk) {
            float4 v0 = *(const float4*)(xrow + kk*32);
            float4 v1 = *(const float4*)(xrow + kk*32 + 4);
            bf16x8 pk;
            pk[0]=(short)f2bf(v0.x); pk[1]=(short)f2bf(v0.y);
            pk[2]=(short)f2bf(v0.z); pk[3]=(short)f2bf(v0.w);
            pk[4]=(short)f2bf(v1.x); pk[5]=(short)f2bf(v1.y);
            pk[6]=(short)f2bf(v1.z); pk[7]=(short)f2bf(v1.w);
            xa[kk] = pk;
        }
    }
    __syncthreads();

    f32x4 acc[8];
    #pragma unroll
    for (int i = 0; i < 8; ++i) acc[i] = (f32x4){0.f,0.f,0.f,0.f};
    #pragma unroll
    for (int kk = 0; kk < 4; ++kk) {
        int kb = kk*64 + lh*16;
        #pragma unroll
        for (int nf = 0; nf < 8; ++nf) {
            int rb = nf*16 + lr;
            bf16x8 b = *(bf16x8*)(Ws + rb*256 + (kb ^ ((rb&7)<<4)));
            acc[nf] = __builtin_amdgcn_mfma_f32_16x16x32_bf16(xa[kk], b, acc[nf], 0, 0, 0);
        }
    }
    #pragma unroll
    for (int nf = 0; nf < 8; ++nf) {
        int col = nf*16 + lr;
        #pragma unroll
        for (int j = 0; j < 4; ++j) {
            int row = m0 + wv*16 + lh*4 + j;
            tout[(size_t)row * C_ + col] = f2bf(acc[nf][j]);
        }
    }
}

// ---------------- vfr gather: x += BN(max_k t[knn] - t) ----------------
__global__ __launch_bounds__(256) void vfr_gather_kernel(
    float* __restrict__ x, const ushort* __restrict__ t,
    const int* __restrict__ knn,
    const float* __restrict__ s, const float* __restrict__ bb)
{
    const int wv   = threadIdx.x >> 6;
    const int lane = threadIdx.x & 63;
    const int p = blockIdx.x * 4 + wv;          // point id 0..63999
    const int b = p / N_;
    const int base = b * N_;
    const int* kp = knn + (size_t)p * K_;
    const uint* trow = (const uint*)t;          // 64 dwords per row

    uint cen = trow[(size_t)p * 64 + lane];
    float c0 = bf2f((ushort)(cen & 0xffffu));
    float c1 = bf2f((ushort)(cen >> 16));
    float m0v = -INFINITY, m1v = -INFINITY;
    #pragma unroll
    for (int k = 0; k < K_; ++k) {
        int idx = kp[k];
        uint g = trow[(size_t)(base + idx) * 64 + lane];
        m0v = fmaxf(m0v, bf2f((ushort)(g & 0xffffu)));
        m1v = fmaxf(m1v, bf2f((ushort)(g >> 16)));
    }
    m0v -= c0; m1v -= c1;

    int c = lane * 2;
    float2 sv = *(const float2*)(s + c);
    float2 bv = *(const float2*)(bb + c);
    size_t o = (size_t)p * C_ + c;
    float2 xv = *(const float2*)(x + o);
    xv.x += m0v * sv.x + bv.x;
    xv.y += m1v * sv.y + bv.y;
    *(float2*)(x + o) = xv;
}

extern "C" void kernel_launch(void* const* d_in, const int* in_sizes, int n_in,
                              void* d_out, int out_size, void* d_ws, size_t ws_size,
                              hipStream_t stream) {
    const float* x      = (const float*)d_in[0];
    const float* pe     = (const float*)d_in[1];
    const int*   knn    = (const int*)d_in[2];
    const float* mlp_W1 = (const float*)d_in[3];
    const float* mlp_b1 = (const float*)d_in[4];
    const float* mlp_W2 = (const float*)d_in[5];
    const float* mlp_g  = (const float*)d_in[6];
    const float* mlp_be = (const float*)d_in[7];
    const float* mlp_m  = (const float*)d_in[8];
    const float* mlp_v  = (const float*)d_in[9];
    const float* vfr_W  = (const float*)d_in[10];
    const float* vfr_g  = (const float*)d_in[11];
    const float* vfr_be = (const float*)d_in[12];
    const float* vfr_m  = (const float*)d_in[13];
    const float* vfr_v  = (const float*)d_in[14];
    const float* ffn_W1 = (const float*)d_in[15];
    const float* ffn_b1 = (const float*)d_in[16];
    const float* ffn_W2 = (const float*)d_in[17];
    const float* ffn_g  = (const float*)d_in[18];
    const float* ffn_be = (const float*)d_in[19];
    const float* ffn_m  = (const float*)d_in[20];
    const float* ffn_v  = (const float*)d_in[21];
    float* out = (float*)d_out;

    char* ws = (char*)d_ws;
    ushort* tbuf = (ushort*)ws;  ws += (size_t)R_ * C_ * 2;       // 16.4 MB
    ushort* w1t  = (ushort*)ws;  ws += (size_t)5 * H_ * C_ * 2;
    ushort* w2p  = (ushort*)ws;  ws += (size_t)5 * C_ * H_ * 2;
    ushort* wvt  = (ushort*)ws;  ws += (size_t)D_ * C_ * C_ * 2;
    float*  b1a  = (float*)ws;   ws += (size_t)5 * H_ * 4;
    float*  fs   = (float*)ws;   ws += (size_t)5 * C_ * 4;
    float*  fb   = (float*)ws;   ws += (size_t)5 * C_ * 4;
    float*  vs   = (float*)ws;   ws += (size_t)D_ * C_ * 4;
    float*  vb   = (float*)ws;   ws += (size_t)D_ * C_ * 4;

    const int prep_items = 2*(5*H_*C_) + D_*C_*C_ + 5*H_ + 5*C_ + D_*C_;
    prep_kernel<<<(prep_items + 255) / 256, 256, 0, stream>>>(
        mlp_W1, mlp_b1, mlp_W2, mlp_g, mlp_be, mlp_m, mlp_v,
        vfr_W, vfr_g, vfr_be, vfr_m, vfr_v,
        ffn_W1, ffn_b1, ffn_W2, ffn_g, ffn_be, ffn_m, ffn_v,
        w1t, w2p, wvt, b1a, fs, fb, vs, vb);

    // x1 = x0 + FFN_mlp(x0) + pe   (pe-add for depth 0 fused into epilogue)
    ffn_kernel<true><<<R_/128, 512, 0, stream>>>(
        x, out, pe, w1t, w2p, b1a, fs, fb);

    for (int d = 0; d < D_; ++d) {
        vfr_gemm_kernel<<<R_/64, 256, 0, stream>>>(
            out, wvt + (size_t)d * C_ * C_, tbuf);
        vfr_gather_kernel<<<R_/4, 256, 0, stream>>>(
            out, tbuf, knn, vs + d * C_, vb + d * C_);
        if (d < D_ - 1) {
            ffn_kernel<true><<<R_/128, 512, 0, stream>>>(
                out, out, pe,
                w1t + (size_t)(d+1) * H_ * C_, w2p + (size_t)(d+1) * C_ * H_,
                b1a + (d+1) * H_, fs + (d+1) * C_, fb + (d+1) * C_);
        } else {
            ffn_kernel<false><<<R_/128, 512, 0, stream>>>(
                out, out, pe,
                w1t + (size_t)(d+1) * H_ * C_, w2p + (size_t)(d+1) * C_ * H_,
                b1a + (d+1) * H_, fs + (d+1) * C_, fb + (d+1) * C_);
        }
    }
}

// Round 4
// 350.939 us; speedup vs baseline: 1.5199x; 1.0436x over previous
//
#include <hip/hip_runtime.h>
#include <hip/hip_bf16.h>

typedef __attribute__((ext_vector_type(8))) short bf16x8;
typedef __attribute__((ext_vector_type(4))) short bf16x4;
typedef __attribute__((ext_vector_type(4))) float f32x4;

#define B_ 4
#define N_ 16000
#define C_ 128
#define K_ 16
#define D_ 4
#define H_ 512
#define R_ (B_*N_)      // 64000 rows
#define EPSV 1e-5f

__device__ __forceinline__ ushort f2bf(float f) {
    uint32_t b = __builtin_bit_cast(uint32_t, f);
    b += 0x7fffu + ((b >> 16) & 1u);   // RNE
    return (ushort)(b >> 16);
}
__device__ __forceinline__ float bf2f(ushort u) {
    return __builtin_bit_cast(float, (uint32_t)u << 16);
}
// gelu_tanh(v) = v * sigmoid(2u), u = 0.79788456*(v + 0.044715 v^3)
__device__ __forceinline__ float gelu_fast(float v) {
    float v2 = v * v;
    float u = v * fmaf(0.0356774081f, v2, 0.7978845608f);
    float e = __expf(-2.0f * u);
    return v * __builtin_amdgcn_rcpf(1.0f + e);
}
// async global->LDS, 16B per lane; lds base must be wave-uniform
__device__ __forceinline__ void gll16(const void* g, void* l) {
    __builtin_amdgcn_global_load_lds(
        (__attribute__((address_space(1))) void*)g,
        (__attribute__((address_space(3))) void*)l, 16, 0, 0);
}

// ---------------- prep: transpose weights bf16, fold BN ----------------
// sigma-permutation (within each 32-k block): slot s=8*lam+j holds
// k = 4*lam + (j&3) + 16*(j>>2). Applied to W2's h-dim and Wv's k-dim so
// the downstream GEMM's A-operand is register-local from the swapped
// upstream GEMM's accumulator fragments.
__global__ void prep_kernel(
    const float* __restrict__ mlp_W1, const float* __restrict__ mlp_b1,
    const float* __restrict__ mlp_W2, const float* __restrict__ mlp_g,
    const float* __restrict__ mlp_be, const float* __restrict__ mlp_m,
    const float* __restrict__ mlp_v,
    const float* __restrict__ vfr_W, const float* __restrict__ vfr_g,
    const float* __restrict__ vfr_be, const float* __restrict__ vfr_m,
    const float* __restrict__ vfr_v,
    const float* __restrict__ ffn_W1, const float* __restrict__ ffn_b1,
    const float* __restrict__ ffn_W2, const float* __restrict__ ffn_g,
    const float* __restrict__ ffn_be, const float* __restrict__ ffn_m,
    const float* __restrict__ ffn_v,
    ushort* __restrict__ w1t, ushort* __restrict__ w2p, ushort* __restrict__ wvs,
    float* __restrict__ b1a, float* __restrict__ fs, float* __restrict__ fb,
    float* __restrict__ vs, float* __restrict__ vb)
{
    int i = blockIdx.x * 256 + threadIdx.x;
    const int NW = 5 * H_ * C_;   // 327680
    if (i < NW) {                 // w1t[f][h][c] = W1_f[c][h]
        int f = i / (H_*C_), e = i % (H_*C_);
        int h = e / C_, c = e % C_;
        const float* src = (f == 0) ? mlp_W1 : ffn_W1 + (size_t)(f-1)*C_*H_;
        w1t[i] = f2bf(src[(size_t)c*H_ + h]);
        return;
    }
    i -= NW;
    if (i < NW) {                 // w2p[f][c][p] = W2_f[sigma(p)][c]
        int f = i / (H_*C_), e = i % (H_*C_);
        int c = e / H_, p = e % H_;
        int s = p & 31, lam = s >> 3, j = s & 7;
        int h = (p & ~31) + lam*4 + (j & 3) + ((j >> 2) << 4);
        const float* src = (f == 0) ? mlp_W2 : ffn_W2 + (size_t)(f-1)*H_*C_;
        w2p[i] = f2bf(src[(size_t)h*C_ + c]);
        return;
    }
    i -= NW;
    if (i < D_*C_*C_) {           // wvs[d][cout][p] = W[d][sigma(p)][cout]
        int d = i / (C_*C_), e = i % (C_*C_);
        int co = e / C_, p = e % C_;
        int s = p & 31, lam = s >> 3, j = s & 7;
        int k = (p & ~31) + lam*4 + (j & 3) + ((j >> 2) << 4);
        wvs[i] = f2bf(vfr_W[(size_t)d*C_*C_ + (size_t)k*C_ + co]);
        return;
    }
    i -= D_*C_*C_;
    if (i < 5*H_) {               // biases
        int f = i / H_, h = i % H_;
        b1a[i] = (f == 0) ? mlp_b1[h] : ffn_b1[(f-1)*H_ + h];
        return;
    }
    i -= 5*H_;
    if (i < 5*C_) {               // ffn BN: y*s + b
        int f = i / C_, c = i % C_;
        float g  = (f==0) ? mlp_g[c]  : ffn_g[(f-1)*C_ + c];
        float be = (f==0) ? mlp_be[c] : ffn_be[(f-1)*C_ + c];
        float m  = (f==0) ? mlp_m[c]  : ffn_m[(f-1)*C_ + c];
        float v  = (f==0) ? mlp_v[c]  : ffn_v[(f-1)*C_ + c];
        float s = g * rsqrtf(v + EPSV);
        fs[i] = s; fb[i] = be - m * s;
        return;
    }
    i -= 5*C_;
    if (i < D_*C_) {              // vfr BN
        float s = vfr_g[i] * rsqrtf(vfr_v[i] + EPSV);
        vs[i] = s; vb[i] = vfr_be[i] - vfr_m[i] * s;
    }
}

// ---- fused FFN (+ next-depth t-GEMM):
//   x_out = x_in [+ pe] + BN(gelu(x_in@W1+b1)@W2)
//   if NEXT_T: t = bf16(x_out @ Wv)   (x_out already includes pe)
// 256 threads / 4 waves / TM=64 (16 rows per wave); 32KB LDS -> 4+ blocks/CU.
// Serial 2-barrier chunk staging (r2 shape: inter-block TLP hides the drain).
// GEMM1 swapped (D[h][m]); GEMM2 swapped too (D[c][m]) so the epilogue's
// x_out fragments feed GEMM3's A-operand register-locally via sigma-permuted Wv.
template<bool ADD_PE, bool NEXT_T>
__global__ __launch_bounds__(256, 4) void ffn_kernel(
    const float* __restrict__ xin, float* __restrict__ xout,
    const float* __restrict__ pe,
    const ushort* __restrict__ W1t,   // [H][C] bf16
    const ushort* __restrict__ W2p,   // [C][H] bf16, sigma-permuted in h
    const float* __restrict__ b1,
    const float* __restrict__ bns, const float* __restrict__ bnb,
    const ushort* __restrict__ Wvs,   // [C][C] bf16, sigma-permuted in k
    ushort* __restrict__ tout)
{
    __shared__ __attribute__((aligned(16))) char lds[32768];
    char* W1s = lds;           // [64 h][256B] swizzled
    char* W2s = lds + 16384;   // [128 c][128B] swizzled

    const int tid  = threadIdx.x;
    const int m0   = blockIdx.x * 64;
    const int wv   = tid >> 6;
    const int lane = tid & 63;
    const int lr   = lane & 15;
    const int lh   = lane >> 4;       // 0..3

    // X A-fragments in registers: row m0+wv*16+lr, k = kk*32 + lh*8 + j
    bf16x8 xa[4];
    {
        const float* xrow = xin + (size_t)(m0 + wv*16 + lr) * C_ + lh*8;
        #pragma unroll
        for (int kk = 0; kk < 4; ++kk) {
            float4 v0 = *(const float4*)(xrow + kk*32);
            float4 v1 = *(const float4*)(xrow + kk*32 + 4);
            bf16x8 pk;
            pk[0]=(short)f2bf(v0.x); pk[1]=(short)f2bf(v0.y);
            pk[2]=(short)f2bf(v0.z); pk[3]=(short)f2bf(v0.w);
            pk[4]=(short)f2bf(v1.x); pk[5]=(short)f2bf(v1.y);
            pk[6]=(short)f2bf(v1.z); pk[7]=(short)f2bf(v1.w);
            xa[kk] = pk;
        }
    }

    f32x4 acc2[8];
    #pragma unroll
    for (int i = 0; i < 8; ++i) acc2[i] = (f32x4){0.f,0.f,0.f,0.f};

    for (int hc = 0; hc < 8; ++hc) {
        const int h0 = hc * 64;
        __syncthreads();               // all waves done reading previous chunk
        // stage W1 chunk: [64 h][256B], 4 rounds x 4KB
        #pragma unroll
        for (int i = 0; i < 4; ++i) {
            int row = i*16 + wv*4 + (lane >> 4);
            const char* src = (const char*)(W1t + (size_t)(h0 + row) * C_)
                            + (((lane & 15) * 16) ^ ((row & 7) << 4));
            gll16(src, W1s + i*4096 + wv*1024);
        }
        // stage W2 chunk: [128 c][128B], 4 rounds x 4KB
        #pragma unroll
        for (int i = 0; i < 4; ++i) {
            int row = i*32 + wv*8 + (lane >> 3);
            const char* src = (const char*)(W2p + (size_t)row * H_ + h0)
                            + (((lane & 7) * 16) ^ ((row & 7) << 4));
            gll16(src, W2s + i*4096 + wv*1024);
        }
        __syncthreads();               // drain: chunk visible

        // GEMM1 swapped: acc1[nf] = P[h = nf*16 + lh*4+j][m = lr]
        f32x4 acc1[4];
        #pragma unroll
        for (int i = 0; i < 4; ++i) acc1[i] = (f32x4){0.f,0.f,0.f,0.f};
        #pragma unroll
        for (int kk = 0; kk < 4; ++kk) {
            int kb = kk*64 + lh*16;
            #pragma unroll
            for (int nf = 0; nf < 4; ++nf) {
                int rb = nf*16 + lr;
                bf16x8 w1 = *(bf16x8*)(W1s + rb*256 + (kb ^ ((rb&7)<<4)));
                acc1[nf] = __builtin_amdgcn_mfma_f32_16x16x32_bf16(w1, xa[kk], acc1[nf], 0, 0, 0);
            }
        }
        // bias + GELU -> bf16 fragments pa[nf]
        bf16x4 pa[4];
        #pragma unroll
        for (int nf = 0; nf < 4; ++nf) {
            float4 bias = *(const float4*)(b1 + h0 + nf*16 + lh*4);
            bf16x4 p;
            p[0] = (short)f2bf(gelu_fast(acc1[nf][0] + bias.x));
            p[1] = (short)f2bf(gelu_fast(acc1[nf][1] + bias.y));
            p[2] = (short)f2bf(gelu_fast(acc1[nf][2] + bias.z));
            p[3] = (short)f2bf(gelu_fast(acc1[nf][3] + bias.w));
            pa[nf] = p;
        }
        // GEMM2 swapped: acc2[nf] = Y[c = nf*16 + lh*4+j][m = lr]
        #pragma unroll
        for (int g = 0; g < 2; ++g) {
            bf16x8 af = __builtin_shufflevector(pa[2*g], pa[2*g+1], 0,1,2,3,4,5,6,7);
            int kb = g*64 + lh*16;
            #pragma unroll
            for (int nf = 0; nf < 8; ++nf) {
                int rb = nf*16 + lr;
                bf16x8 w2 = *(bf16x8*)(W2s + rb*128 + (kb ^ ((rb&7)<<4)));
                acc2[nf] = __builtin_amdgcn_mfma_f32_16x16x32_bf16(w2, af, acc2[nf], 0, 0, 0);
            }
        }
    }

    // ---- tail: epilogue (+ optional fused t-GEMM) ----
    if (NEXT_T) {
        __syncthreads();               // all waves done reading last chunk
        // stage Wvs: [128 cout][256B k-slots], 8 rounds x 4KB (covered by epilogue)
        #pragma unroll
        for (int i = 0; i < 8; ++i) {
            int r = i*16 + wv*4 + (lane >> 4);
            const char* src = (const char*)(Wvs + (size_t)r * C_)
                            + (((lane & 15) * 16) ^ ((r & 7) << 4));
            gll16(src, lds + i*4096 + wv*1024);
        }
    }

    const int row = m0 + wv*16 + lr;
    bf16x4 pa2[8];
    #pragma unroll
    for (int nf = 0; nf < 8; ++nf) {
        int c0 = nf*16 + lh*4;
        float4 sv = *(const float4*)(bns + c0);
        float4 bv = *(const float4*)(bnb + c0);
        float4 xi = *(const float4*)(xin + (size_t)row * C_ + c0);
        if (ADD_PE) {
            float4 pv = *(const float4*)(pe + (size_t)row * C_ + c0);
            xi.x += pv.x; xi.y += pv.y; xi.z += pv.z; xi.w += pv.w;
        }
        float4 xo;
        xo.x = xi.x + acc2[nf][0] * sv.x + bv.x;
        xo.y = xi.y + acc2[nf][1] * sv.y + bv.y;
        xo.z = xi.z + acc2[nf][2] * sv.z + bv.z;
        xo.w = xi.w + acc2[nf][3] * sv.w + bv.w;
        *(float4*)(xout + (size_t)row * C_ + c0) = xo;
        if (NEXT_T) {
            bf16x4 p;
            p[0] = (short)f2bf(xo.x); p[1] = (short)f2bf(xo.y);
            p[2] = (short)f2bf(xo.z); p[3] = (short)f2bf(xo.w);
            pa2[nf] = p;
        }
    }

    if (NEXT_T) {
        __syncthreads();               // Wvs staged + visible
        f32x4 acc3[8];
        #pragma unroll
        for (int i = 0; i < 8; ++i) acc3[i] = (f32x4){0.f,0.f,0.f,0.f};
        #pragma unroll
        for (int g = 0; g < 4; ++g) {
            bf16x8 af = __builtin_shufflevector(pa2[2*g], pa2[2*g+1], 0,1,2,3,4,5,6,7);
            int kb = g*64 + lh*16;
            #pragma unroll
            for (int nf = 0; nf < 8; ++nf) {
                int rb = nf*16 + lr;
                bf16x8 b = *(bf16x8*)(lds + rb*256 + (kb ^ ((rb&7)<<4)));
                acc3[nf] = __builtin_amdgcn_mfma_f32_16x16x32_bf16(af, b, acc3[nf], 0, 0, 0);
            }
        }
        #pragma unroll
        for (int nf = 0; nf < 8; ++nf) {
            int col = nf*16 + lr;
            #pragma unroll
            for (int j = 0; j < 4; ++j) {
                int trow = m0 + wv*16 + lh*4 + j;
                tout[(size_t)trow * C_ + col] = f2bf(acc3[nf][j]);
            }
        }
    }
}

// ---------------- vfr gather: x += BN(max_k t[knn] - t) ----------------
__global__ __launch_bounds__(256) void vfr_gather_kernel(
    float* __restrict__ x, const ushort* __restrict__ t,
    const int* __restrict__ knn,
    const float* __restrict__ s, const float* __restrict__ bb)
{
    const int wv   = threadIdx.x >> 6;
    const int lane = threadIdx.x & 63;
    const int p = blockIdx.x * 4 + wv;          // point id 0..63999
    const int b = p / N_;
    const int base = b * N_;
    const int* kp = knn + (size_t)p * K_;
    const uint* trow = (const uint*)t;          // 64 dwords per row

    uint cen = trow[(size_t)p * 64 + lane];
    float c0 = bf2f((ushort)(cen & 0xffffu));
    float c1 = bf2f((ushort)(cen >> 16));
    float m0v = -INFINITY, m1v = -INFINITY;
    #pragma unroll
    for (int k = 0; k < K_; ++k) {
        int idx = kp[k];
        uint g = trow[(size_t)(base + idx) * 64 + lane];
        m0v = fmaxf(m0v, bf2f((ushort)(g & 0xffffu)));
        m1v = fmaxf(m1v, bf2f((ushort)(g >> 16)));
    }
    m0v -= c0; m1v -= c1;

    int c = lane * 2;
    float2 sv = *(const float2*)(s + c);
    float2 bv = *(const float2*)(bb + c);
    size_t o = (size_t)p * C_ + c;
    float2 xv = *(const float2*)(x + o);
    xv.x += m0v * sv.x + bv.x;
    xv.y += m1v * sv.y + bv.y;
    *(float2*)(x + o) = xv;
}

extern "C" void kernel_launch(void* const* d_in, const int* in_sizes, int n_in,
                              void* d_out, int out_size, void* d_ws, size_t ws_size,
                              hipStream_t stream) {
    const float* x      = (const float*)d_in[0];
    const float* pe     = (const float*)d_in[1];
    const int*   knn    = (const int*)d_in[2];
    const float* mlp_W1 = (const float*)d_in[3];
    const float* mlp_b1 = (const float*)d_in[4];
    const float* mlp_W2 = (const float*)d_in[5];
    const float* mlp_g  = (const float*)d_in[6];
    const float* mlp_be = (const float*)d_in[7];
    const float* mlp_m  = (const float*)d_in[8];
    const float* mlp_v  = (const float*)d_in[9];
    const float* vfr_W  = (const float*)d_in[10];
    const float* vfr_g  = (const float*)d_in[11];
    const float* vfr_be = (const float*)d_in[12];
    const float* vfr_m  = (const float*)d_in[13];
    const float* vfr_v  = (const float*)d_in[14];
    const float* ffn_W1 = (const float*)d_in[15];
    const float* ffn_b1 = (const float*)d_in[16];
    const float* ffn_W2 = (const float*)d_in[17];
    const float* ffn_g  = (const float*)d_in[18];
    const float* ffn_be = (const float*)d_in[19];
    const float* ffn_m  = (const float*)d_in[20];
    const float* ffn_v  = (const float*)d_in[21];
    float* out = (float*)d_out;

    char* ws = (char*)d_ws;
    ushort* tbuf = (ushort*)ws;  ws += (size_t)R_ * C_ * 2;       // 16.4 MB
    ushort* w1t  = (ushort*)ws;  ws += (size_t)5 * H_ * C_ * 2;
    ushort* w2p  = (ushort*)ws;  ws += (size_t)5 * C_ * H_ * 2;
    ushort* wvs  = (ushort*)ws;  ws += (size_t)D_ * C_ * C_ * 2;
    float*  b1a  = (float*)ws;   ws += (size_t)5 * H_ * 4;
    float*  fs   = (float*)ws;   ws += (size_t)5 * C_ * 4;
    float*  fb   = (float*)ws;   ws += (size_t)5 * C_ * 4;
    float*  vs   = (float*)ws;   ws += (size_t)D_ * C_ * 4;
    float*  vb   = (float*)ws;   ws += (size_t)D_ * C_ * 4;

    const int prep_items = 2*(5*H_*C_) + D_*C_*C_ + 5*H_ + 5*C_ + D_*C_;
    prep_kernel<<<(prep_items + 255) / 256, 256, 0, stream>>>(
        mlp_W1, mlp_b1, mlp_W2, mlp_g, mlp_be, mlp_m, mlp_v,
        vfr_W, vfr_g, vfr_be, vfr_m, vfr_v,
        ffn_W1, ffn_b1, ffn_W2, ffn_g, ffn_be, ffn_m, ffn_v,
        w1t, w2p, wvs, b1a, fs, fb, vs, vb);

    // x1 = x0 + FFN_mlp(x0) + pe ; t0 = x1' @ Wv0 fused
    ffn_kernel<true, true><<<R_/64, 256, 0, stream>>>(
        x, out, pe, w1t, w2p, b1a, fs, fb, wvs, tbuf);

    for (int d = 0; d < D_; ++d) {
        vfr_gather_kernel<<<R_/4, 256, 0, stream>>>(
            out, tbuf, knn, vs + d * C_, vb + d * C_);
        if (d < D_ - 1) {
            ffn_kernel<true, true><<<R_/64, 256, 0, stream>>>(
                out, out, pe,
                w1t + (size_t)(d+1) * H_ * C_, w2p + (size_t)(d+1) * C_ * H_,
                b1a + (d+1) * H_, fs + (d+1) * C_, fb + (d+1) * C_,
                wvs + (size_t)(d+1) * C_ * C_, tbuf);
        } else {
            ffn_kernel<false, false><<<R_/64, 256, 0, stream>>>(
                out, out, pe,
                w1t + (size_t)(d+1) * H_ * C_, w2p + (size_t)(d+1) * C_ * H_,
                b1a + (d+1) * H_, fs + (d+1) * C_, fb + (d+1) * C_,
                wvs, tbuf);
        }
    }
}